// Round 1
// baseline (659.213 us; speedup 1.0000x reference)
//
#include <hip/hip_runtime.h>
#include <hip/hip_bf16.h>

#define BATCH 16
#define NN 1024
#define MM 1024
#define DD 512

#define LOG2E 1.4426950408889634f
#define LN2f  0.6931471805599453f
#define NEGS  -1.442695e9f   // NEG (-1e9) scaled by log2e; acts as -inf sentinel

// nw_dp geometry: 8 waves/block, 2 rows/lane, stagger 80 cols, barrier every 16
#define WAVES 8
#define DSTAG 80              // inter-wave column stagger (= 64 + barrier period)
#define PF    16              // theta prefetch depth == unroll == barrier period
#define GTOT  1648            // >= 1023 + 7*DSTAG + 63 + 1 = 1647, multiple of PF

typedef __bf16 v8bf __attribute__((ext_vector_type(8)));
typedef __bf16 v4bf __attribute__((ext_vector_type(4)));
typedef float  v4f  __attribute__((ext_vector_type(4)));

// ---------------------------------------------------------------- zero A acc
__global__ void zero_acc(float* a) {
    if (threadIdx.x < BATCH) a[threadIdx.x] = 0.0f;
}

// ------------------------------------------- fp32->bf16 convert + gap-dot
__global__ __launch_bounds__(256) void conv_reduce(
        const float* __restrict__ zx, const float* __restrict__ zy,
        const float* __restrict__ gw,
        __bf16* __restrict__ zxb, __bf16* __restrict__ zyb,
        float* __restrict__ acc) {
    const int chunk = blockIdx.x, b = blockIdx.y, which = blockIdx.z;
    const float* src = which ? zy : zx;
    __bf16* dst = which ? zyb : zxb;
    const float* g = gw + which * DD;
    const size_t base = ((size_t)b * NN + (size_t)chunk * 64) * DD;
    const int t = threadIdx.x;
    const int col = (t * 4) & (DD - 1);
    const float4 gv = *(const float4*)(g + col);
    float sum = 0.0f;
    #pragma unroll 4
    for (int it = 0; it < 32; ++it) {
        size_t off = base + (size_t)it * 1024 + t * 4;
        float4 x = *(const float4*)(src + off);
        sum += x.x * gv.x + x.y * gv.y + x.z * gv.z + x.w * gv.w;
        v4bf o = { (__bf16)x.x, (__bf16)x.y, (__bf16)x.z, (__bf16)x.w };
        *(v4bf*)(dst + off) = o;
    }
    #pragma unroll
    for (int o = 32; o > 0; o >>= 1) sum += __shfl_down(sum, o);
    __shared__ float wsum[4];
    if ((t & 63) == 0) wsum[t >> 6] = sum;
    __syncthreads();
    if (t == 0) {
        float s = wsum[0] + wsum[1] + wsum[2] + wsum[3];
        atomicAdd(acc + b, s * (1.0f / 1024.0f));
    }
}

// ------------------------------------------------------- bf16 MFMA NT GEMM
// out[row i][col j] = sum_d A[i,d]*B[j,d].  Called with A=zyb, B=zxb so the
// output buffer is thetaT[j_theta][i_theta] (theta transposed) at zero cost.
__global__ __launch_bounds__(256) void gemm_bt(
        const __bf16* __restrict__ Abf, const __bf16* __restrict__ Bbf,
        float* __restrict__ theta) {
    __shared__ __bf16 As[64 * 40];
    __shared__ __bf16 Bs[64 * 40];
    const int b = blockIdx.z;
    const int i0 = blockIdx.y * 64, j0 = blockIdx.x * 64;
    const __bf16* ap = Abf + ((size_t)b * NN + i0) * DD;
    const __bf16* bp = Bbf + ((size_t)b * MM + j0) * DD;
    const int t = threadIdx.x;
    const int srow = t >> 2, scol = (t & 3) * 8;
    const int lane = t & 63, wave = t >> 6;
    const int mrow = lane & 15, quad = lane >> 4;
    v4f acc[4] = {};
    for (int kk = 0; kk < DD; kk += 32) {
        if (kk) __syncthreads();
        *(v8bf*)&As[srow * 40 + scol] = *(const v8bf*)(ap + (size_t)srow * DD + kk + scol);
        *(v8bf*)&Bs[srow * 40 + scol] = *(const v8bf*)(bp + (size_t)srow * DD + kk + scol);
        __syncthreads();
        v8bf af = *(const v8bf*)&As[(wave * 16 + mrow) * 40 + quad * 8];
        #pragma unroll
        for (int tt = 0; tt < 4; ++tt) {
            v8bf bf = *(const v8bf*)&Bs[(tt * 16 + mrow) * 40 + quad * 8];
            acc[tt] = __builtin_amdgcn_mfma_f32_16x16x32_bf16(af, bf, acc[tt], 0, 0, 0);
        }
    }
    const size_t tb = (size_t)b * NN * MM;
    #pragma unroll
    for (int tt = 0; tt < 4; ++tt) {
        int j = j0 + tt * 16 + mrow;
        #pragma unroll
        for (int r = 0; r < 4; ++r) {
            int i = i0 + wave * 16 + quad * 4 + r;
            theta[tb + (size_t)i * MM + j] = acc[tt][r];
        }
    }
}

// --------------------------------------------------- soft-NW wavefront DP
// 8 waves per batch (512 threads). Wave w owns V-rows 128w+1..128w+128,
// lane t owns 2 rows. Wave w staggered DSTAG=80 cols behind wave w-1;
// boundary crosses waves via a 256-slot LDS ring, barrier every 16 iters
// (write->read gap is exactly 16 iters => exactly one barrier between).
// 2 waves per SIMD (vs 1 before): the second wave fills the ~54% of cycles
// the serial DP dependence chain leaves idle.
// Single-shuffle trick: diag input tp at iter g == post-fixup tc of iter g-1
// (incl. the lane-0 ring case), so one ds_bpermute + one ring read per iter.
// lse3 trick: the max term is exp2(0)=1 -> ss = 1 + exp2(med-mx) + exp2(min-mx)
// via v_max3/v_med3/v_min3 (one fewer transcendental per cell, same math).
__global__ __launch_bounds__(512) void nw_dp(
        const float* __restrict__ thetaT, const float* __restrict__ acc,
        const float* __restrict__ gap_b, float* __restrict__ out) {
    const int b = blockIdx.x;
    const int tid = threadIdx.x;
    const int t = tid & 63, w = tid >> 6;
    const float Ac = (acc[b] + gap_b[0]) * LOG2E;
    const int row0 = w * 128 + t * 2;          // theta rows row0, row0+1
    const int off = w * DSTAG + t;             // lane's column lag
    const float* Tb = thetaT + (size_t)b * NN * MM + row0;

    __shared__ float ring[WAVES - 1][256];

    float v0 = NEGS, v1 = NEGS;                // carried row values (left inputs)
    float v3c = NEGS;                          // bottom-row value, prev iter
    float tcp = NEGS;                          // prev iteration's tc (post-fixup)

    float2 pf[PF];
    #pragma unroll
    for (int u = 0; u < PF; ++u) {
        int c0 = u - off;
        c0 = c0 < 0 ? 0 : c0;                  // u-off <= 15 < MM, only low clamp
        pf[u] = *(const float2*)(Tb + (size_t)c0 * NN);
    }
    float rtc = NEGS;                          // prefetched ring value (lane 0, w>0)

    for (int gg = 0; gg < GTOT; gg += PF) {
        #pragma unroll
        for (int u = 0; u < PF; ++u) {
            const int g = gg + u;
            const int c = g - off;

            float tc = __shfl_up(v3c, 1);      // up input: V[row0][c+1]
            if (t == 0) tc = (w == 0) ? NEGS : rtc;
            float tp = tcp;                    // diag input: V[row0][c] == prev tc
            if (t == 0 && c == 0) tp = (w == 0) ? 0.0f : NEGS;
            tcp = tc;

            const float2 cur = pf[u];
            // re-issue this slot: column g + PF - off
            int cn = g + PF - off;
            cn = cn < 0 ? 0 : (cn > MM - 1 ? MM - 1 : cn);
            pf[u] = *(const float2*)(Tb + (size_t)cn * NN);

            if (c >= 0 && c < MM) {
                float up_in = tc, dg = tp;
                {   // row 0
                    float left = v0;
                    float up = up_in + Ac;
                    float lf = left + Ac;
                    float mx = fmaxf(fmaxf(up, dg), lf);
                    float md = __builtin_amdgcn_fmed3f(up, dg, lf);
                    float mn = fminf(fminf(up, dg), lf);
                    float ss = 1.0f + __builtin_amdgcn_exp2f(md - mx)
                                    + __builtin_amdgcn_exp2f(mn - mx);
                    float nv = fmaf(cur.x, LOG2E, mx + __builtin_amdgcn_logf(ss));
                    dg = left;      // next row's diag = V[row][c]
                    up_in = nv;     // next row's up   = V[row][c+1]
                    v0 = nv;
                }
                {   // row 1
                    float left = v1;
                    float up = up_in + Ac;
                    float lf = left + Ac;
                    float mx = fmaxf(fmaxf(up, dg), lf);
                    float md = __builtin_amdgcn_fmed3f(up, dg, lf);
                    float mn = fminf(fminf(up, dg), lf);
                    float ss = 1.0f + __builtin_amdgcn_exp2f(md - mx)
                                    + __builtin_amdgcn_exp2f(mn - mx);
                    v1 = fmaf(cur.y, LOG2E, mx + __builtin_amdgcn_logf(ss));
                }
                v3c = v1;
                if (t == 63 && w < WAVES - 1) ring[w][c & 255] = v1;
            }

            if (u == PF - 1) __syncthreads();  // compile-time: barrier every 16 iters

            // ring prefetch for iteration g+1 (ordered by the barrier pattern:
            // producer wrote column g+1-off exactly 16 iterations earlier, with
            // exactly one barrier strictly between write and this read).
            if (t == 0 && w > 0) rtc = ring[w - 1][(g + 1 - off) & 255];
        }
    }
    if (tid == 511) out[b] = v1 * LN2f;
}

// ---------------------------------------------------------------- launcher
extern "C" void kernel_launch(void* const* d_in, const int* in_sizes, int n_in,
                              void* d_out, int out_size, void* d_ws, size_t ws_size,
                              hipStream_t stream) {
    const float* zx    = (const float*)d_in[0];
    const float* zy    = (const float*)d_in[1];
    const float* gw    = (const float*)d_in[2];
    const float* gapb  = (const float*)d_in[3];
    float* out = (float*)d_out;

    char* ws = (char*)d_ws;
    float*  thetaT = (float*)ws;                                  // 67,108,864 B
    __bf16* zxb   = (__bf16*)(ws + (size_t)67108864);             // 16,777,216 B
    __bf16* zyb   = (__bf16*)(ws + (size_t)67108864 + 16777216);  // 16,777,216 B
    float*  acc   = (float*)(ws + (size_t)67108864 + 2 * 16777216);

    zero_acc<<<1, 64, 0, stream>>>(acc);
    conv_reduce<<<dim3(16, BATCH, 2), 256, 0, stream>>>(zx, zy, gw, zxb, zyb, acc);
    // swapped args: output = theta^T
    gemm_bt<<<dim3(MM / 64, NN / 64, BATCH), 256, 0, stream>>>(zyb, zxb, thetaT);
    nw_dp<<<BATCH, 512, 0, stream>>>(thetaT, acc, gapb, out);
}